// Round 13
// baseline (192.633 us; speedup 1.0000x reference)
//
#include <hip/hip_runtime.h>
#include <hip/hip_bf16.h>

#define Bb 64
#define Ll 200
#define NSs 1000
#define Dd 128
#define Mm 50
#define CCk 8            // scan chunks
#define TT 25            // steps per chunk

__device__ __forceinline__ float bcast_lane(float v, int l) {
    return __int_as_float(__builtin_amdgcn_readlane(__float_as_int(v), l));
}

// ============ kernel 1: precompute tables (dedupe by embedding index) ============
// blocks [0,63):   etab/atab rows x0=blk*32..  (2000 x-rows)
// blocks [63,126): wtab rows sk0=(blk-63)*16.. (1000 sk-rows, softmax)
// blocks [126,158): fk rows sk0=(blk-126)*32.. (k-half of f GEMV, 1000 sk-rows)
__global__ void __launch_bounds__(256) kern_tab(
        const float* __restrict__ k_emb,
        const float* __restrict__ v_emb,
        const float* __restrict__ Mk,
        const float* __restrict__ e_W, const float* __restrict__ e_b,
        const float* __restrict__ a_W, const float* __restrict__ a_b,
        const float* __restrict__ f_W,
        float* __restrict__ wtab, float* __restrict__ etab,
        float* __restrict__ atab, float* __restrict__ fktab) {
    __shared__ float smem[12672];                 // 50.7 KB union
    int tid = threadIdx.x;
    int wave = tid >> 6, lane = tid & 63;

    if (blockIdx.x >= 63 && blockIdx.x < 126) {
        int sk0 = (blockIdx.x - 63) * 16;
        float (*mk)[Dd + 4] = (float(*)[Dd + 4])smem;           // 6600 f
        float (*kr)[Dd + 4] = (float(*)[Dd + 4])(smem + 6600);  // 2112 f
        for (int lin = tid; lin < (Mm * Dd) / 4; lin += 256) {
            float4 f = ((const float4*)Mk)[lin];
            *(float4*)&mk[lin >> 5][(lin & 31) * 4] = f;
        }
        for (int lin = tid; lin < 16 * 32; lin += 256) {
            int r = lin >> 5, c4 = lin & 31;
            int sk = min(sk0 + r, NSs - 1);
            float4 f = ((const float4*)(k_emb + (size_t)sk * Dd))[c4];
            *(float4*)&kr[r][c4 * 4] = f;
        }
        __syncthreads();
        int mmr = (lane < Mm) ? lane : 0;
        float acc[4] = {0.f, 0.f, 0.f, 0.f};
#pragma unroll 2
        for (int q = 0; q < 32; ++q) {
            float4 mkv = *(const float4*)&mk[mmr][q * 4];
#pragma unroll
            for (int i = 0; i < 4; ++i) {
                float4 kv = *(const float4*)&kr[wave * 4 + i][q * 4];
                acc[i] = fmaf(mkv.x, kv.x, acc[i]);
                acc[i] = fmaf(mkv.y, kv.y, acc[i]);
                acc[i] = fmaf(mkv.z, kv.z, acc[i]);
                acc[i] = fmaf(mkv.w, kv.w, acc[i]);
            }
        }
#pragma unroll
        for (int i = 0; i < 4; ++i) {
            float logit = (lane < Mm) ? acc[i] : -1e30f;
            float mx = logit;
            for (int off = 32; off > 0; off >>= 1) mx = fmaxf(mx, __shfl_down(mx, off));
            mx = __shfl(mx, 0);
            float ex = (lane < Mm) ? expf(logit - mx) : 0.f;
            float sm = ex;
            for (int off = 32; off > 0; off >>= 1) sm += __shfl_down(sm, off);
            sm = __shfl(sm, 0);
            int sk = sk0 + wave * 4 + i;
            if (sk < NSs && lane < Mm) wtab[(size_t)sk * Mm + lane] = ex / sm;
        }
        return;
    }

    bool is_fk = (blockIdx.x >= 126);
    int r0 = is_fk ? (blockIdx.x - 126) * 32 : blockIdx.x * 32;
    int rmax = is_fk ? NSs : 2 * NSs;
    const float* src = is_fk ? k_emb : v_emb;

    float (*vt)[Dd + 4] = (float(*)[Dd + 4])smem;           // 4224 f
    float (*wt)[Dd + 4] = (float(*)[Dd + 4])(smem + 4224);  // 8448 f
#pragma unroll
    for (int i = 0; i < 4; ++i) {
        int lin = i * 256 + tid;
        int r = lin >> 5, c4 = lin & 31;
        int x = min(r0 + r, rmax - 1);
        float4 f = ((const float4*)(src + (size_t)x * Dd))[c4];
        *(float4*)&vt[r][c4 * 4] = f;
    }
    __syncthreads();
    int pg = lane >> 3, og = lane & 7;

    if (is_fk) {
        for (int sub = 0; sub < 2; ++sub) {
#pragma unroll
            for (int i = 0; i < 8; ++i) {
                int lin = i * 64 + lane;
                int r = lin >> 5, c4 = lin & 31;
                int row = wave * 32 + sub * 16 + r;
                float4 f = ((const float4*)(f_W + (size_t)row * (2 * Dd)))[32 + c4];
                *(float4*)&wt[wave * 16 + r][c4 * 4] = f;
            }
            float acc[4][2] = {};
#pragma unroll 2
            for (int q = 0; q < 32; ++q) {
                float4 av[4], bv[2];
#pragma unroll
                for (int i = 0; i < 4; ++i) av[i] = *(const float4*)&vt[pg + 8 * i][q * 4];
#pragma unroll
                for (int j = 0; j < 2; ++j) bv[j] = *(const float4*)&wt[wave * 16 + og + 8 * j][q * 4];
#pragma unroll
                for (int i = 0; i < 4; ++i)
#pragma unroll
                    for (int j = 0; j < 2; ++j) {
                        acc[i][j] = fmaf(av[i].x, bv[j].x, acc[i][j]);
                        acc[i][j] = fmaf(av[i].y, bv[j].y, acc[i][j]);
                        acc[i][j] = fmaf(av[i].z, bv[j].z, acc[i][j]);
                        acc[i][j] = fmaf(av[i].w, bv[j].w, acc[i][j]);
                    }
            }
#pragma unroll
            for (int j = 0; j < 2; ++j) {
                int row = wave * 32 + sub * 16 + og + 8 * j;
#pragma unroll
                for (int i = 0; i < 4; ++i) {
                    int sk = r0 + pg + 8 * i;
                    if (sk < NSs) fktab[(size_t)sk * Dd + row] = acc[i][j];
                }
            }
        }
    } else {
        for (int s = 0; s < 4; ++s) {
            int base_row = wave * 64 + s * 16;
            bool is_e = base_row < 128;
            const float* W = is_e ? e_W : a_W;
            int wrow0 = is_e ? base_row : base_row - 128;
#pragma unroll
            for (int i = 0; i < 8; ++i) {
                int lin = i * 64 + lane;
                int r = lin >> 5, c4 = lin & 31;
                float4 f = ((const float4*)(W + (size_t)(wrow0 + r) * Dd))[c4];
                *(float4*)&wt[wave * 16 + r][c4 * 4] = f;
            }
            float acc[4][2] = {};
#pragma unroll 2
            for (int q = 0; q < 32; ++q) {
                float4 av[4], bv[2];
#pragma unroll
                for (int i = 0; i < 4; ++i) av[i] = *(const float4*)&vt[pg + 8 * i][q * 4];
#pragma unroll
                for (int j = 0; j < 2; ++j) bv[j] = *(const float4*)&wt[wave * 16 + og + 8 * j][q * 4];
#pragma unroll
                for (int i = 0; i < 4; ++i)
#pragma unroll
                    for (int j = 0; j < 2; ++j) {
                        acc[i][j] = fmaf(av[i].x, bv[j].x, acc[i][j]);
                        acc[i][j] = fmaf(av[i].y, bv[j].y, acc[i][j]);
                        acc[i][j] = fmaf(av[i].z, bv[j].z, acc[i][j]);
                        acc[i][j] = fmaf(av[i].w, bv[j].w, acc[i][j]);
                    }
            }
            float* dst = is_e ? etab : atab;
#pragma unroll
            for (int j = 0; j < 2; ++j) {
                int row = wrow0 + og + 8 * j;
                float bias = (is_e ? e_b : a_b)[row];
#pragma unroll
                for (int i = 0; i < 4; ++i) {
                    int x = r0 + pg + 8 * i;
                    if (x < 2 * NSs) {
                        float v = acc[i][j] + bias;
                        dst[(size_t)x * Dd + row] = is_e ? (1.f / (1.f + expf(-v))) : tanhf(v);
                    }
                }
            }
        }
    }
}

#define TB_LOAD(S, tt) do { int _t = (tt);                                   \
    if (_t < TT) {                                                           \
        int _sk = __shfl(skv, _t);                                           \
        int _x  = __shfl(xv, _t);                                            \
        w##S = (lane < Mm) ? wtab[(size_t)_sk * Mm + lane] : 0.f;            \
        e##S = etab[(size_t)_x * Dd + d];                                    \
        a##S = atab[(size_t)_x * Dd + d]; } } while (0)

#define PQ_BODY(S) do {                                                      \
    _Pragma("unroll")                                                        \
    for (int m = 0; m < Mm; ++m) {                                           \
        float wm = bcast_lane(w##S, m);                                      \
        float A  = fmaf(-wm, e##S, 1.f);                                     \
        Q[m] = fmaf(A, Q[m], wm * a##S);                                     \
        P[m] *= A; } } while (0)

#define RD_BODY(S, tt) do {                                                  \
    float acc0 = 0.f, acc1 = 0.f;                                            \
    _Pragma("unroll")                                                        \
    for (int m = 0; m < Mm; m += 2) {                                        \
        float wm0 = bcast_lane(w##S, m);                                     \
        float wm1 = bcast_lane(w##S, m + 1);                                 \
        acc0 = fmaf(wm0, mv[m], acc0);                                       \
        mv[m] = fmaf(wm0, fmaf(-e##S, mv[m], a##S), mv[m]);                  \
        acc1 = fmaf(wm1, mv[m + 1], acc1);                                   \
        mv[m + 1] = fmaf(wm1, fmaf(-e##S, mv[m + 1], a##S), mv[m + 1]);      \
    }                                                                        \
    rt[(tt)][d] = acc0 + acc1;                                               \
    } while (0)

// ============ scan pass 1: per-chunk affine transfer (chunks 0..6 only) ============
__global__ void __launch_bounds__(128) kern_scan_pq(
        const int* __restrict__ skills,
        const int* __restrict__ responses,
        const float* __restrict__ wtab,
        const float* __restrict__ etab,
        const float* __restrict__ atab,
        float* __restrict__ P_ws, float* __restrict__ Q_ws) {
    int b = blockIdx.x / (CCk - 1), c = blockIdx.x % (CCk - 1);
    int d = threadIdx.x;
    int lane = d & 63;
    size_t blBase = (size_t)b * Ll + (size_t)c * TT;

    int skv = 0, xv = 0;
    if (lane < TT) {
        skv = skills[blBase + lane];
        int rr = responses[blBase + lane];
        xv = skv + NSs * ((rr > -1) ? rr : 0);
    }

    float P[Mm], Q[Mm];
#pragma unroll
    for (int m = 0; m < Mm; ++m) { P[m] = 1.f; Q[m] = 0.f; }

    float w0 = 0.f, e0 = 0.f, a0 = 0.f;
    float w1 = 0.f, e1 = 0.f, a1 = 0.f;
    float w2 = 0.f, e2 = 0.f, a2 = 0.f;
    TB_LOAD(0, 0);
    TB_LOAD(1, 1);
    for (int tt = 0; tt < TT; tt += 3) {
        TB_LOAD(2, tt + 2);  PQ_BODY(0);
        if (tt + 1 < TT) { TB_LOAD(0, tt + 3);  PQ_BODY(1); }
        if (tt + 2 < TT) { TB_LOAD(1, tt + 4);  PQ_BODY(2); }
    }
    size_t base = ((size_t)(b * (CCk - 1) + c)) * (Mm * Dd) + d;
#pragma unroll
    for (int m = 0; m < Mm; ++m) {
        P_ws[base + m * Dd] = P[m];
        Q_ws[base + m * Dd] = Q[m];
    }
}

// ============ fused scan+head: rescan chunk (read in LDS) then output p ============
// 256 thr: waves 0-1 scan (d=tid<128); waves 2-3 stage fW read-half + fk rows.
// Then all 4 waves: head GEMM over the chunk's 25 positions.
__global__ void __launch_bounds__(256) kern_rd_out(
        const int* __restrict__ skills,
        const int* __restrict__ responses,
        const float* __restrict__ Mv0,
        const float* __restrict__ wtab,
        const float* __restrict__ etab,
        const float* __restrict__ atab,
        const float* __restrict__ P_ws, const float* __restrict__ Q_ws,
        const float* __restrict__ fktab,
        const float* __restrict__ f_W, const float* __restrict__ f_b,
        const float* __restrict__ p_W, const float* __restrict__ p_b,
        float* __restrict__ out) {
    __shared__ float wtile[Dd][Dd + 4];     // fW read-half   (16896 f, 67.6 KB)
    __shared__ float rt[TT][Dd + 4];        // read rows      (3300 f)
    __shared__ float fkt[TT][Dd + 4];       // fk rows        (3300 f)
    __shared__ float pf[32][4];
    int tid = threadIdx.x;
    int b = blockIdx.x / CCk, c = blockIdx.x % CCk;
    size_t blBase = (size_t)b * Ll + (size_t)c * TT;

    if (tid < 128) {
        // ---- scan waves ----
        int d = tid;
        int lane = d & 63;
        int skv = 0, xv = 0;
        if (lane < TT) {
            skv = skills[blBase + lane];
            int rr = responses[blBase + lane];
            xv = skv + NSs * ((rr > -1) ? rr : 0);
        }
        float mv[Mm];
#pragma unroll
        for (int m = 0; m < Mm; ++m) mv[m] = Mv0[m * Dd + d];
        for (int cc = 0; cc < c; ++cc) {
            size_t base = ((size_t)(b * (CCk - 1) + cc)) * (Mm * Dd) + d;
#pragma unroll
            for (int m = 0; m < Mm; ++m)
                mv[m] = fmaf(P_ws[base + m * Dd], mv[m], Q_ws[base + m * Dd]);
        }
        float w0 = 0.f, e0 = 0.f, a0 = 0.f;
        float w1 = 0.f, e1 = 0.f, a1 = 0.f;
        float w2 = 0.f, e2 = 0.f, a2 = 0.f;
        TB_LOAD(0, 0);
        TB_LOAD(1, 1);
        for (int tt = 0; tt < TT; tt += 3) {
            TB_LOAD(2, tt + 2);  RD_BODY(0, tt);
            if (tt + 1 < TT) { TB_LOAD(0, tt + 3);  RD_BODY(1, tt + 1); }
            if (tt + 2 < TT) { TB_LOAD(1, tt + 4);  RD_BODY(2, tt + 2); }
        }
    } else {
        // ---- staging waves: fW read-half (4096 float4) + fk rows (800 float4) ----
        int u = tid - 128;
#pragma unroll
        for (int i = 0; i < 32; ++i) {
            int lin = i * 128 + u;
            int r = lin >> 5, c4 = lin & 31;
            float4 f = ((const float4*)(f_W + (size_t)r * (2 * Dd)))[c4];
            *(float4*)&wtile[r][c4 * 4] = f;
        }
        for (int lin = u; lin < TT * 32; lin += 128) {
            int r = lin >> 5, c4 = lin & 31;
            int sk = skills[blBase + r];
            float4 f = ((const float4*)(fktab + (size_t)sk * Dd))[c4];
            *(float4*)&fkt[r][c4 * 4] = f;
        }
    }
    __syncthreads();

    // ---- head GEMM: 25 positions x 128 rows, K=128 ----
    int wave = tid >> 6, lane = tid & 63;
    int pg = lane >> 3, og = lane & 7;

    float acc[4][4] = {};
#pragma unroll 2
    for (int q = 0; q < 32; ++q) {
        float4 av[4], bv[4];
#pragma unroll
        for (int i = 0; i < 4; ++i) {
            int pos = pg + 8 * i;
            av[i] = *(const float4*)&rt[(pos < TT) ? pos : 0][q * 4];
        }
#pragma unroll
        for (int j = 0; j < 4; ++j) bv[j] = *(const float4*)&wtile[wave * 32 + og + 8 * j][q * 4];
#pragma unroll
        for (int i = 0; i < 4; ++i)
#pragma unroll
            for (int j = 0; j < 4; ++j) {
                acc[i][j] = fmaf(av[i].x, bv[j].x, acc[i][j]);
                acc[i][j] = fmaf(av[i].y, bv[j].y, acc[i][j]);
                acc[i][j] = fmaf(av[i].z, bv[j].z, acc[i][j]);
                acc[i][j] = fmaf(av[i].w, bv[j].w, acc[i][j]);
            }
    }

    float ppart[4] = {0.f, 0.f, 0.f, 0.f};
#pragma unroll
    for (int j = 0; j < 4; ++j) {
        int row = wave * 32 + og + 8 * j;
        float fb = f_b[row];
        float pw = p_W[row];
#pragma unroll
        for (int i = 0; i < 4; ++i) {
            int pos = pg + 8 * i;
            float fkv = fkt[(pos < TT) ? pos : 0][row];
            ppart[i] = fmaf(tanhf(acc[i][j] + fkv + fb), pw, ppart[i]);
        }
    }
#pragma unroll
    for (int i = 0; i < 4; ++i) {
        float v = ppart[i];
        for (int off = 4; off > 0; off >>= 1) v += __shfl_down(v, off, 8);
        if (og == 0) pf[pg + 8 * i][wave] = v;
    }
    __syncthreads();
    if (tid < 32 && tid < TT) {
        int l = c * TT + tid;                     // global position
        if (l >= 1) {
            float s = pf[tid][0] + pf[tid][1] + pf[tid][2] + pf[tid][3] + p_b[0];
            out[b * (Ll - 1) + (l - 1)] = 1.f / (1.f + expf(-s));
        }
    }
}

extern "C" void kernel_launch(void* const* d_in, const int* in_sizes, int n_in,
                              void* d_out, int out_size, void* d_ws, size_t ws_size,
                              hipStream_t stream) {
    const int*   skills    = (const int*)  d_in[0];
    const int*   responses = (const int*)  d_in[1];
    const float* k_emb     = (const float*)d_in[2];
    const float* v_emb     = (const float*)d_in[3];
    const float* Mk        = (const float*)d_in[4];
    const float* Mv0       = (const float*)d_in[5];
    const float* e_W       = (const float*)d_in[6];
    const float* e_b       = (const float*)d_in[7];
    const float* a_W       = (const float*)d_in[8];
    const float* a_b       = (const float*)d_in[9];
    const float* f_W       = (const float*)d_in[10];
    const float* f_b       = (const float*)d_in[11];
    const float* p_W       = (const float*)d_in[12];
    const float* p_b       = (const float*)d_in[13];
    (void)in_sizes; (void)n_in; (void)out_size; (void)ws_size;

    float* out = (float*)d_out;

    const size_t BMD = (size_t)Bb * Mm * Dd;     // 409,600

    float* ws      = (float*)d_ws;
    float* P_ws    = ws;                          // 7*BMD
    float* Q_ws    = P_ws + (CCk - 1) * BMD;      // 7*BMD
    float* wtab    = Q_ws + (CCk - 1) * BMD;      // 1000*50
    float* etab    = wtab + (size_t)NSs * Mm;     // 2000*128
    float* atab    = etab + (size_t)2 * NSs * Dd; // 2000*128
    float* fktab   = atab + (size_t)2 * NSs * Dd; // 1000*128

    kern_tab<<<158, 256, 0, stream>>>(k_emb, v_emb, Mk, e_W, e_b, a_W, a_b, f_W,
                                      wtab, etab, atab, fktab);
    kern_scan_pq<<<Bb * (CCk - 1), 128, 0, stream>>>(skills, responses,
                                                     wtab, etab, atab, P_ws, Q_ws);
    kern_rd_out<<<Bb * CCk, 256, 0, stream>>>(skills, responses, Mv0,
                                              wtab, etab, atab, P_ws, Q_ws,
                                              fktab, f_W, f_b, p_W, p_b, out);
}

// Round 14
// 166.955 us; speedup vs baseline: 1.1538x; 1.1538x over previous
//
#include <hip/hip_runtime.h>
#include <hip/hip_bf16.h>

#define Bb 64
#define Ll 200
#define NSs 1000
#define Dd 128
#define Mm 50
#define CCk 20           // scan chunks
#define TT 10            // steps per chunk

__device__ __forceinline__ float bcast_lane(float v, int l) {
    return __int_as_float(__builtin_amdgcn_readlane(__float_as_int(v), l));
}

// ============ kernel 1: precompute tables (dedupe by embedding index) ============
// blocks [0,63):   etab/atab rows x0=blk*32..  (2000 x-rows)
// blocks [63,126): wtab rows sk0=(blk-63)*16.. (1000 sk-rows, softmax)
// blocks [126,158): fk rows sk0=(blk-126)*32.. (k-half of f GEMV, 1000 sk-rows)
__global__ void __launch_bounds__(256) kern_tab(
        const float* __restrict__ k_emb,
        const float* __restrict__ v_emb,
        const float* __restrict__ Mk,
        const float* __restrict__ e_W, const float* __restrict__ e_b,
        const float* __restrict__ a_W, const float* __restrict__ a_b,
        const float* __restrict__ f_W,
        float* __restrict__ wtab, float* __restrict__ etab,
        float* __restrict__ atab, float* __restrict__ fktab) {
    __shared__ float smem[12672];                 // 50.7 KB union
    int tid = threadIdx.x;
    int wave = tid >> 6, lane = tid & 63;

    if (blockIdx.x >= 63 && blockIdx.x < 126) {
        int sk0 = (blockIdx.x - 63) * 16;
        float (*mk)[Dd + 4] = (float(*)[Dd + 4])smem;           // 6600 f
        float (*kr)[Dd + 4] = (float(*)[Dd + 4])(smem + 6600);  // 2112 f
        for (int lin = tid; lin < (Mm * Dd) / 4; lin += 256) {
            float4 f = ((const float4*)Mk)[lin];
            *(float4*)&mk[lin >> 5][(lin & 31) * 4] = f;
        }
        for (int lin = tid; lin < 16 * 32; lin += 256) {
            int r = lin >> 5, c4 = lin & 31;
            int sk = min(sk0 + r, NSs - 1);
            float4 f = ((const float4*)(k_emb + (size_t)sk * Dd))[c4];
            *(float4*)&kr[r][c4 * 4] = f;
        }
        __syncthreads();
        int mmr = (lane < Mm) ? lane : 0;
        float acc[4] = {0.f, 0.f, 0.f, 0.f};
#pragma unroll 2
        for (int q = 0; q < 32; ++q) {
            float4 mkv = *(const float4*)&mk[mmr][q * 4];
#pragma unroll
            for (int i = 0; i < 4; ++i) {
                float4 kv = *(const float4*)&kr[wave * 4 + i][q * 4];
                acc[i] = fmaf(mkv.x, kv.x, acc[i]);
                acc[i] = fmaf(mkv.y, kv.y, acc[i]);
                acc[i] = fmaf(mkv.z, kv.z, acc[i]);
                acc[i] = fmaf(mkv.w, kv.w, acc[i]);
            }
        }
#pragma unroll
        for (int i = 0; i < 4; ++i) {
            float logit = (lane < Mm) ? acc[i] : -1e30f;
            float mx = logit;
            for (int off = 32; off > 0; off >>= 1) mx = fmaxf(mx, __shfl_down(mx, off));
            mx = __shfl(mx, 0);
            float ex = (lane < Mm) ? expf(logit - mx) : 0.f;
            float sm = ex;
            for (int off = 32; off > 0; off >>= 1) sm += __shfl_down(sm, off);
            sm = __shfl(sm, 0);
            int sk = sk0 + wave * 4 + i;
            if (sk < NSs && lane < Mm) wtab[(size_t)sk * Mm + lane] = ex / sm;
        }
        return;
    }

    bool is_fk = (blockIdx.x >= 126);
    int r0 = is_fk ? (blockIdx.x - 126) * 32 : blockIdx.x * 32;
    int rmax = is_fk ? NSs : 2 * NSs;
    const float* src = is_fk ? k_emb : v_emb;

    float (*vt)[Dd + 4] = (float(*)[Dd + 4])smem;           // 4224 f
    float (*wt)[Dd + 4] = (float(*)[Dd + 4])(smem + 4224);  // 8448 f
#pragma unroll
    for (int i = 0; i < 4; ++i) {
        int lin = i * 256 + tid;
        int r = lin >> 5, c4 = lin & 31;
        int x = min(r0 + r, rmax - 1);
        float4 f = ((const float4*)(src + (size_t)x * Dd))[c4];
        *(float4*)&vt[r][c4 * 4] = f;
    }
    __syncthreads();
    int pg = lane >> 3, og = lane & 7;

    if (is_fk) {
        for (int sub = 0; sub < 2; ++sub) {
#pragma unroll
            for (int i = 0; i < 8; ++i) {
                int lin = i * 64 + lane;
                int r = lin >> 5, c4 = lin & 31;
                int row = wave * 32 + sub * 16 + r;
                float4 f = ((const float4*)(f_W + (size_t)row * (2 * Dd)))[32 + c4];
                *(float4*)&wt[wave * 16 + r][c4 * 4] = f;
            }
            float acc[4][2] = {};
#pragma unroll 2
            for (int q = 0; q < 32; ++q) {
                float4 av[4], bv[2];
#pragma unroll
                for (int i = 0; i < 4; ++i) av[i] = *(const float4*)&vt[pg + 8 * i][q * 4];
#pragma unroll
                for (int j = 0; j < 2; ++j) bv[j] = *(const float4*)&wt[wave * 16 + og + 8 * j][q * 4];
#pragma unroll
                for (int i = 0; i < 4; ++i)
#pragma unroll
                    for (int j = 0; j < 2; ++j) {
                        acc[i][j] = fmaf(av[i].x, bv[j].x, acc[i][j]);
                        acc[i][j] = fmaf(av[i].y, bv[j].y, acc[i][j]);
                        acc[i][j] = fmaf(av[i].z, bv[j].z, acc[i][j]);
                        acc[i][j] = fmaf(av[i].w, bv[j].w, acc[i][j]);
                    }
            }
#pragma unroll
            for (int j = 0; j < 2; ++j) {
                int row = wave * 32 + sub * 16 + og + 8 * j;
#pragma unroll
                for (int i = 0; i < 4; ++i) {
                    int sk = r0 + pg + 8 * i;
                    if (sk < NSs) fktab[(size_t)sk * Dd + row] = acc[i][j];
                }
            }
        }
    } else {
        for (int s = 0; s < 4; ++s) {
            int base_row = wave * 64 + s * 16;
            bool is_e = base_row < 128;
            const float* W = is_e ? e_W : a_W;
            int wrow0 = is_e ? base_row : base_row - 128;
#pragma unroll
            for (int i = 0; i < 8; ++i) {
                int lin = i * 64 + lane;
                int r = lin >> 5, c4 = lin & 31;
                float4 f = ((const float4*)(W + (size_t)(wrow0 + r) * Dd))[c4];
                *(float4*)&wt[wave * 16 + r][c4 * 4] = f;
            }
            float acc[4][2] = {};
#pragma unroll 2
            for (int q = 0; q < 32; ++q) {
                float4 av[4], bv[2];
#pragma unroll
                for (int i = 0; i < 4; ++i) av[i] = *(const float4*)&vt[pg + 8 * i][q * 4];
#pragma unroll
                for (int j = 0; j < 2; ++j) bv[j] = *(const float4*)&wt[wave * 16 + og + 8 * j][q * 4];
#pragma unroll
                for (int i = 0; i < 4; ++i)
#pragma unroll
                    for (int j = 0; j < 2; ++j) {
                        acc[i][j] = fmaf(av[i].x, bv[j].x, acc[i][j]);
                        acc[i][j] = fmaf(av[i].y, bv[j].y, acc[i][j]);
                        acc[i][j] = fmaf(av[i].z, bv[j].z, acc[i][j]);
                        acc[i][j] = fmaf(av[i].w, bv[j].w, acc[i][j]);
                    }
            }
            float* dst = is_e ? etab : atab;
#pragma unroll
            for (int j = 0; j < 2; ++j) {
                int row = wrow0 + og + 8 * j;
                float bias = (is_e ? e_b : a_b)[row];
#pragma unroll
                for (int i = 0; i < 4; ++i) {
                    int x = r0 + pg + 8 * i;
                    if (x < 2 * NSs) {
                        float v = acc[i][j] + bias;
                        dst[(size_t)x * Dd + row] = is_e ? (1.f / (1.f + expf(-v))) : tanhf(v);
                    }
                }
            }
        }
    }
}

#define TB_LOAD(S, tt) do { int _t = (tt);                                   \
    if (_t < TT) {                                                           \
        int _sk = __shfl(skv, _t);                                           \
        int _x  = __shfl(xv, _t);                                            \
        w##S = (lane < Mm) ? wtab[(size_t)_sk * Mm + lane] : 0.f;            \
        e##S = etab[(size_t)_x * Dd + d];                                    \
        a##S = atab[(size_t)_x * Dd + d]; } } while (0)

#define PQ_BODY(S) do {                                                      \
    _Pragma("unroll")                                                        \
    for (int m = 0; m < Mm; ++m) {                                           \
        float wm = bcast_lane(w##S, m);                                      \
        float A  = fmaf(-wm, e##S, 1.f);                                     \
        Q[m] = fmaf(A, Q[m], wm * a##S);                                     \
        P[m] *= A; } } while (0)

#define RD_BODY(S, tt) do {                                                  \
    float acc0 = 0.f, acc1 = 0.f;                                            \
    _Pragma("unroll")                                                        \
    for (int m = 0; m < Mm; m += 2) {                                        \
        float wm0 = bcast_lane(w##S, m);                                     \
        float wm1 = bcast_lane(w##S, m + 1);                                 \
        acc0 = fmaf(wm0, mv[m], acc0);                                       \
        mv[m] = fmaf(wm0, fmaf(-e##S, mv[m], a##S), mv[m]);                  \
        acc1 = fmaf(wm1, mv[m + 1], acc1);                                   \
        mv[m + 1] = fmaf(wm1, fmaf(-e##S, mv[m + 1], a##S), mv[m + 1]);      \
    }                                                                        \
    read_ws[(blBase + (tt)) * Dd + d] = acc0 + acc1;                         \
    } while (0)

// ============ scan pass 1: per-chunk affine transfer (chunks 0..CCk-2) ============
__global__ void __launch_bounds__(128) kern_scan_pq(
        const int* __restrict__ skills,
        const int* __restrict__ responses,
        const float* __restrict__ wtab,
        const float* __restrict__ etab,
        const float* __restrict__ atab,
        float* __restrict__ P_ws, float* __restrict__ Q_ws) {
    int b = blockIdx.x / (CCk - 1), c = blockIdx.x % (CCk - 1);
    int d = threadIdx.x;
    int lane = d & 63;
    size_t blBase = (size_t)b * Ll + (size_t)c * TT;

    int skv = 0, xv = 0;
    if (lane < TT) {
        skv = skills[blBase + lane];
        int rr = responses[blBase + lane];
        xv = skv + NSs * ((rr > -1) ? rr : 0);
    }

    float P[Mm], Q[Mm];
#pragma unroll
    for (int m = 0; m < Mm; ++m) { P[m] = 1.f; Q[m] = 0.f; }

    float w0 = 0.f, e0 = 0.f, a0 = 0.f;
    float w1 = 0.f, e1 = 0.f, a1 = 0.f;
    float w2 = 0.f, e2 = 0.f, a2 = 0.f;
    TB_LOAD(0, 0);
    TB_LOAD(1, 1);
    for (int tt = 0; tt < TT; tt += 3) {
        TB_LOAD(2, tt + 2);  PQ_BODY(0);
        if (tt + 1 < TT) { TB_LOAD(0, tt + 3);  PQ_BODY(1); }
        if (tt + 2 < TT) { TB_LOAD(1, tt + 4);  PQ_BODY(2); }
    }
    size_t base = ((size_t)(b * (CCk - 1) + c)) * (Mm * Dd) + d;
#pragma unroll
    for (int m = 0; m < Mm; ++m) {
        P_ws[base + m * Dd] = P[m];
        Q_ws[base + m * Dd] = Q[m];
    }
}

// ============ scan pass 2: chunk-boundary combine (all loads hoisted) ============
__global__ void kern_scan_comb(
        const float* __restrict__ Mv0,
        const float* __restrict__ P_ws, const float* __restrict__ Q_ws,
        float* __restrict__ S_ws) {
    int idx = blockIdx.x * 256 + threadIdx.x;     // 0 .. B*M*D-1
    int b   = idx / (Mm * Dd);
    int md  = idx % (Mm * Dd);
    float Pr[CCk - 1], Qr[CCk - 1];
#pragma unroll
    for (int c = 0; c < CCk - 1; ++c) {           // all loads issued together
        size_t pq = ((size_t)(b * (CCk - 1) + c)) * (Mm * Dd) + md;
        Pr[c] = P_ws[pq];
        Qr[c] = Q_ws[pq];
    }
    float s = Mv0[md];
#pragma unroll
    for (int c = 0; c < CCk - 1; ++c) {
        s = fmaf(Pr[c], s, Qr[c]);
        S_ws[((size_t)(b * (CCk - 1) + c)) * (Mm * Dd) + md] = s;
    }
}

// ============ scan pass 3: rescan chunk from known start, emit read ============
__global__ void __launch_bounds__(128) kern_scan_rd(
        const int* __restrict__ skills,
        const int* __restrict__ responses,
        const float* __restrict__ Mv0,
        const float* __restrict__ wtab,
        const float* __restrict__ etab,
        const float* __restrict__ atab,
        const float* __restrict__ S_ws,
        float* __restrict__ read_ws) {
    int b = blockIdx.x / CCk, c = blockIdx.x % CCk;
    int d = threadIdx.x;
    int lane = d & 63;
    size_t blBase = (size_t)b * Ll + (size_t)c * TT;

    int skv = 0, xv = 0;
    if (lane < TT) {
        skv = skills[blBase + lane];
        int rr = responses[blBase + lane];
        xv = skv + NSs * ((rr > -1) ? rr : 0);
    }

    float mv[Mm];
    if (c == 0) {
#pragma unroll
        for (int m = 0; m < Mm; ++m) mv[m] = Mv0[m * Dd + d];
    } else {
        size_t sb = ((size_t)(b * (CCk - 1) + (c - 1))) * (Mm * Dd) + d;
#pragma unroll
        for (int m = 0; m < Mm; ++m) mv[m] = S_ws[sb + m * Dd];
    }

    float w0 = 0.f, e0 = 0.f, a0 = 0.f;
    float w1 = 0.f, e1 = 0.f, a1 = 0.f;
    float w2 = 0.f, e2 = 0.f, a2 = 0.f;
    TB_LOAD(0, 0);
    TB_LOAD(1, 1);
    for (int tt = 0; tt < TT; tt += 3) {
        TB_LOAD(2, tt + 2);  RD_BODY(0, tt);
        if (tt + 1 < TT) { TB_LOAD(0, tt + 3);  RD_BODY(1, tt + 1); }
        if (tt + 2 < TT) { TB_LOAD(1, tt + 4);  RD_BODY(2, tt + 2); }
    }
}

// ============ kernel 4: p = sigmoid(tanh(read·fW1 + fk[sk] + fb) @ pW^T + pb) ============
// 32 pos/block, 4 waves; K=128 (read half only). Lane tile 4 pos x 2 rows.
__global__ void __launch_bounds__(256) kern_out(
        const int* __restrict__ skills,
        const float* __restrict__ read_ws,
        const float* __restrict__ fktab,
        const float* __restrict__ f_W, const float* __restrict__ f_b,
        const float* __restrict__ p_W, const float* __restrict__ p_b,
        float* __restrict__ out) {
    __shared__ float ct[32][Dd + 4];           // read rows       (4224 f)
    __shared__ float fkt[32][Dd + 4];          // fk rows by sk   (4224 f)
    __shared__ float wt[4][16][Dd + 4];        // f_W read-half   (8448 f)
    __shared__ float pf[32][8];
    int tid = threadIdx.x;
    int blk = blockIdx.x;

#pragma unroll
    for (int i = 0; i < 4; ++i) {
        int lin = i * 256 + tid;
        int r = lin >> 5, c4 = lin & 31;
        int idx = blk * 32 + r;
        int b = idx / (Ll - 1);
        int l = idx % (Ll - 1) + 1;
        int bl = b * Ll + l;
        float4 f = ((const float4*)(read_ws + (size_t)bl * Dd))[c4];
        *(float4*)&ct[r][c4 * 4] = f;
        int sk = skills[bl];
        float4 g = ((const float4*)(fktab + (size_t)sk * Dd))[c4];
        *(float4*)&fkt[r][c4 * 4] = g;
    }
    ((float*)pf)[tid] = 0.f;
    __syncthreads();

    int wave = tid >> 6, lane = tid & 63;
    int pg = lane >> 3, og = lane & 7;

    float ppart[4] = {0.f, 0.f, 0.f, 0.f};
    for (int sub = 0; sub < 2; ++sub) {
        float acc[4][2] = {};
#pragma unroll
        for (int i = 0; i < 8; ++i) {
            int lin = i * 64 + lane;
            int r = lin >> 5, c4 = lin & 31;
            int row = wave * 32 + sub * 16 + r;
            float4 f = ((const float4*)(f_W + (size_t)row * (2 * Dd)))[c4];
            *(float4*)&wt[wave][r][c4 * 4] = f;
        }
        // wave-private tile: no barrier
#pragma unroll 2
        for (int q = 0; q < 32; ++q) {
            float4 av[4], bv[2];
#pragma unroll
            for (int i = 0; i < 4; ++i) av[i] = *(const float4*)&ct[pg + 8 * i][q * 4];
#pragma unroll
            for (int j = 0; j < 2; ++j) bv[j] = *(const float4*)&wt[wave][og + 8 * j][q * 4];
#pragma unroll
            for (int i = 0; i < 4; ++i)
#pragma unroll
                for (int j = 0; j < 2; ++j) {
                    acc[i][j] = fmaf(av[i].x, bv[j].x, acc[i][j]);
                    acc[i][j] = fmaf(av[i].y, bv[j].y, acc[i][j]);
                    acc[i][j] = fmaf(av[i].z, bv[j].z, acc[i][j]);
                    acc[i][j] = fmaf(av[i].w, bv[j].w, acc[i][j]);
                }
        }
#pragma unroll
        for (int j = 0; j < 2; ++j) {
            int row = wave * 32 + sub * 16 + og + 8 * j;
            float fb = f_b[row];
            float pw = p_W[row];
#pragma unroll
            for (int i = 0; i < 4; ++i) {
                float fkv = fkt[pg + 8 * i][row];
                ppart[i] = fmaf(tanhf(acc[i][j] + fkv + fb), pw, ppart[i]);
            }
        }
    }
#pragma unroll
    for (int i = 0; i < 4; ++i) {
        float v = ppart[i];
        for (int off = 4; off > 0; off >>= 1) v += __shfl_down(v, off, 8);
        if (og == 0) pf[pg + 8 * i][wave] = v;
    }
    __syncthreads();
    if (tid < 32) {
        float s = pf[tid][0] + pf[tid][1] + pf[tid][2] + pf[tid][3] + p_b[0];
        out[blk * 32 + tid] = 1.f / (1.f + expf(-s));
    }
}

extern "C" void kernel_launch(void* const* d_in, const int* in_sizes, int n_in,
                              void* d_out, int out_size, void* d_ws, size_t ws_size,
                              hipStream_t stream) {
    const int*   skills    = (const int*)  d_in[0];
    const int*   responses = (const int*)  d_in[1];
    const float* k_emb     = (const float*)d_in[2];
    const float* v_emb     = (const float*)d_in[3];
    const float* Mk        = (const float*)d_in[4];
    const float* Mv0       = (const float*)d_in[5];
    const float* e_W       = (const float*)d_in[6];
    const float* e_b       = (const float*)d_in[7];
    const float* a_W       = (const float*)d_in[8];
    const float* a_b       = (const float*)d_in[9];
    const float* f_W       = (const float*)d_in[10];
    const float* f_b       = (const float*)d_in[11];
    const float* p_W       = (const float*)d_in[12];
    const float* p_b       = (const float*)d_in[13];
    (void)in_sizes; (void)n_in; (void)out_size; (void)ws_size;

    float* out = (float*)d_out;

    const size_t BLD = (size_t)Bb * Ll * Dd;     // 1,638,400
    const size_t BMD = (size_t)Bb * Mm * Dd;     // 409,600

    float* ws      = (float*)d_ws;
    float* read_ws = ws;                          // BLD
    float* P_ws    = read_ws + BLD;               // (CCk-1)*BMD
    float* Q_ws    = P_ws + (CCk - 1) * BMD;      // (CCk-1)*BMD
    float* S_ws    = Q_ws + (CCk - 1) * BMD;      // (CCk-1)*BMD
    float* wtab    = S_ws + (CCk - 1) * BMD;      // 1000*50
    float* etab    = wtab + (size_t)NSs * Mm;     // 2000*128
    float* atab    = etab + (size_t)2 * NSs * Dd; // 2000*128
    float* fktab   = atab + (size_t)2 * NSs * Dd; // 1000*128

    kern_tab<<<158, 256, 0, stream>>>(k_emb, v_emb, Mk, e_W, e_b, a_W, a_b, f_W,
                                      wtab, etab, atab, fktab);
    kern_scan_pq<<<Bb * (CCk - 1), 128, 0, stream>>>(skills, responses,
                                                     wtab, etab, atab, P_ws, Q_ws);
    kern_scan_comb<<<(int)(BMD / 256), 256, 0, stream>>>(Mv0, P_ws, Q_ws, S_ws);
    kern_scan_rd<<<Bb * CCk, 128, 0, stream>>>(skills, responses, Mv0,
                                               wtab, etab, atab, S_ws, read_ws);
    kern_out<<<Bb * (Ll - 1) / 32, 256, 0, stream>>>(skills, read_ws, fktab,
                                                     f_W, f_b, p_W, p_b, out);
}

// Round 15
// 158.632 us; speedup vs baseline: 1.2143x; 1.0525x over previous
//
#include <hip/hip_runtime.h>
#include <hip/hip_bf16.h>

#define Bb 64
#define Ll 200
#define NSs 1000
#define Dd 128
#define Mm 50
#define CCk 20           // scan chunks
#define TT 10            // steps per chunk

using bf16t = __hip_bfloat16;

__device__ __forceinline__ float bcast_lane(float v, int l) {
    return __int_as_float(__builtin_amdgcn_readlane(__float_as_int(v), l));
}

// ============ kernel 1: precompute tables (dedupe by embedding index) ============
// blocks [0,63):   etab/atab rows x0=blk*32..  (2000 x-rows)
// blocks [63,126): wtab rows sk0=(blk-63)*16.. (1000 sk-rows, softmax)
// blocks [126,158): fk rows sk0=(blk-126)*32.. (k-half of f GEMV, 1000 sk-rows)
__global__ void __launch_bounds__(256) kern_tab(
        const float* __restrict__ k_emb,
        const float* __restrict__ v_emb,
        const float* __restrict__ Mk,
        const float* __restrict__ e_W, const float* __restrict__ e_b,
        const float* __restrict__ a_W, const float* __restrict__ a_b,
        const float* __restrict__ f_W,
        float* __restrict__ wtab, float* __restrict__ etab,
        float* __restrict__ atab, float* __restrict__ fktab) {
    __shared__ float smem[12672];                 // 50.7 KB union
    int tid = threadIdx.x;
    int wave = tid >> 6, lane = tid & 63;

    if (blockIdx.x >= 63 && blockIdx.x < 126) {
        int sk0 = (blockIdx.x - 63) * 16;
        float (*mk)[Dd + 4] = (float(*)[Dd + 4])smem;           // 6600 f
        float (*kr)[Dd + 4] = (float(*)[Dd + 4])(smem + 6600);  // 2112 f
        for (int lin = tid; lin < (Mm * Dd) / 4; lin += 256) {
            float4 f = ((const float4*)Mk)[lin];
            *(float4*)&mk[lin >> 5][(lin & 31) * 4] = f;
        }
        for (int lin = tid; lin < 16 * 32; lin += 256) {
            int r = lin >> 5, c4 = lin & 31;
            int sk = min(sk0 + r, NSs - 1);
            float4 f = ((const float4*)(k_emb + (size_t)sk * Dd))[c4];
            *(float4*)&kr[r][c4 * 4] = f;
        }
        __syncthreads();
        int mmr = (lane < Mm) ? lane : 0;
        float acc[4] = {0.f, 0.f, 0.f, 0.f};
#pragma unroll 2
        for (int q = 0; q < 32; ++q) {
            float4 mkv = *(const float4*)&mk[mmr][q * 4];
#pragma unroll
            for (int i = 0; i < 4; ++i) {
                float4 kv = *(const float4*)&kr[wave * 4 + i][q * 4];
                acc[i] = fmaf(mkv.x, kv.x, acc[i]);
                acc[i] = fmaf(mkv.y, kv.y, acc[i]);
                acc[i] = fmaf(mkv.z, kv.z, acc[i]);
                acc[i] = fmaf(mkv.w, kv.w, acc[i]);
            }
        }
#pragma unroll
        for (int i = 0; i < 4; ++i) {
            float logit = (lane < Mm) ? acc[i] : -1e30f;
            float mx = logit;
            for (int off = 32; off > 0; off >>= 1) mx = fmaxf(mx, __shfl_down(mx, off));
            mx = __shfl(mx, 0);
            float ex = (lane < Mm) ? expf(logit - mx) : 0.f;
            float sm = ex;
            for (int off = 32; off > 0; off >>= 1) sm += __shfl_down(sm, off);
            sm = __shfl(sm, 0);
            int sk = sk0 + wave * 4 + i;
            if (sk < NSs && lane < Mm) wtab[(size_t)sk * Mm + lane] = ex / sm;
        }
        return;
    }

    bool is_fk = (blockIdx.x >= 126);
    int r0 = is_fk ? (blockIdx.x - 126) * 32 : blockIdx.x * 32;
    int rmax = is_fk ? NSs : 2 * NSs;
    const float* src = is_fk ? k_emb : v_emb;

    float (*vt)[Dd + 4] = (float(*)[Dd + 4])smem;           // 4224 f
    float (*wt)[Dd + 4] = (float(*)[Dd + 4])(smem + 4224);  // 8448 f
#pragma unroll
    for (int i = 0; i < 4; ++i) {
        int lin = i * 256 + tid;
        int r = lin >> 5, c4 = lin & 31;
        int x = min(r0 + r, rmax - 1);
        float4 f = ((const float4*)(src + (size_t)x * Dd))[c4];
        *(float4*)&vt[r][c4 * 4] = f;
    }
    __syncthreads();
    int pg = lane >> 3, og = lane & 7;

    if (is_fk) {
        for (int sub = 0; sub < 2; ++sub) {
#pragma unroll
            for (int i = 0; i < 8; ++i) {
                int lin = i * 64 + lane;
                int r = lin >> 5, c4 = lin & 31;
                int row = wave * 32 + sub * 16 + r;
                float4 f = ((const float4*)(f_W + (size_t)row * (2 * Dd)))[32 + c4];
                *(float4*)&wt[wave * 16 + r][c4 * 4] = f;
            }
            float acc[4][2] = {};
#pragma unroll 2
            for (int q = 0; q < 32; ++q) {
                float4 av[4], bv[2];
#pragma unroll
                for (int i = 0; i < 4; ++i) av[i] = *(const float4*)&vt[pg + 8 * i][q * 4];
#pragma unroll
                for (int j = 0; j < 2; ++j) bv[j] = *(const float4*)&wt[wave * 16 + og + 8 * j][q * 4];
#pragma unroll
                for (int i = 0; i < 4; ++i)
#pragma unroll
                    for (int j = 0; j < 2; ++j) {
                        acc[i][j] = fmaf(av[i].x, bv[j].x, acc[i][j]);
                        acc[i][j] = fmaf(av[i].y, bv[j].y, acc[i][j]);
                        acc[i][j] = fmaf(av[i].z, bv[j].z, acc[i][j]);
                        acc[i][j] = fmaf(av[i].w, bv[j].w, acc[i][j]);
                    }
            }
#pragma unroll
            for (int j = 0; j < 2; ++j) {
                int row = wave * 32 + sub * 16 + og + 8 * j;
#pragma unroll
                for (int i = 0; i < 4; ++i) {
                    int sk = r0 + pg + 8 * i;
                    if (sk < NSs) fktab[(size_t)sk * Dd + row] = acc[i][j];
                }
            }
        }
    } else {
        for (int s = 0; s < 4; ++s) {
            int base_row = wave * 64 + s * 16;
            bool is_e = base_row < 128;
            const float* W = is_e ? e_W : a_W;
            int wrow0 = is_e ? base_row : base_row - 128;
#pragma unroll
            for (int i = 0; i < 8; ++i) {
                int lin = i * 64 + lane;
                int r = lin >> 5, c4 = lin & 31;
                float4 f = ((const float4*)(W + (size_t)(wrow0 + r) * Dd))[c4];
                *(float4*)&wt[wave * 16 + r][c4 * 4] = f;
            }
            float acc[4][2] = {};
#pragma unroll 2
            for (int q = 0; q < 32; ++q) {
                float4 av[4], bv[2];
#pragma unroll
                for (int i = 0; i < 4; ++i) av[i] = *(const float4*)&vt[pg + 8 * i][q * 4];
#pragma unroll
                for (int j = 0; j < 2; ++j) bv[j] = *(const float4*)&wt[wave * 16 + og + 8 * j][q * 4];
#pragma unroll
                for (int i = 0; i < 4; ++i)
#pragma unroll
                    for (int j = 0; j < 2; ++j) {
                        acc[i][j] = fmaf(av[i].x, bv[j].x, acc[i][j]);
                        acc[i][j] = fmaf(av[i].y, bv[j].y, acc[i][j]);
                        acc[i][j] = fmaf(av[i].z, bv[j].z, acc[i][j]);
                        acc[i][j] = fmaf(av[i].w, bv[j].w, acc[i][j]);
                    }
            }
            float* dst = is_e ? etab : atab;
#pragma unroll
            for (int j = 0; j < 2; ++j) {
                int row = wrow0 + og + 8 * j;
                float bias = (is_e ? e_b : a_b)[row];
#pragma unroll
                for (int i = 0; i < 4; ++i) {
                    int x = r0 + pg + 8 * i;
                    if (x < 2 * NSs) {
                        float v = acc[i][j] + bias;
                        dst[(size_t)x * Dd + row] = is_e ? (1.f / (1.f + expf(-v))) : tanhf(v);
                    }
                }
            }
        }
    }
}

#define TB_LOAD(S, tt) do { int _t = (tt);                                   \
    if (_t < TT) {                                                           \
        int _sk = __shfl(skv, _t);                                           \
        int _x  = __shfl(xv, _t);                                            \
        w##S = (lane < Mm) ? wtab[(size_t)_sk * Mm + lane] : 0.f;            \
        e##S = etab[(size_t)_x * Dd + d];                                    \
        a##S = atab[(size_t)_x * Dd + d]; } } while (0)

#define PQ_BODY(S) do {                                                      \
    _Pragma("unroll")                                                        \
    for (int m = 0; m < Mm; ++m) {                                           \
        float wm = bcast_lane(w##S, m);                                      \
        float A  = fmaf(-wm, e##S, 1.f);                                     \
        Q[m] = fmaf(A, Q[m], wm * a##S);                                     \
        P[m] *= A; } } while (0)

#define RD_BODY(S, tt) do {                                                  \
    float acc0 = 0.f, acc1 = 0.f;                                            \
    _Pragma("unroll")                                                        \
    for (int m = 0; m < Mm; m += 2) {                                        \
        float wm0 = bcast_lane(w##S, m);                                     \
        float wm1 = bcast_lane(w##S, m + 1);                                 \
        acc0 = fmaf(wm0, mv[m], acc0);                                       \
        mv[m] = fmaf(wm0, fmaf(-e##S, mv[m], a##S), mv[m]);                  \
        acc1 = fmaf(wm1, mv[m + 1], acc1);                                   \
        mv[m + 1] = fmaf(wm1, fmaf(-e##S, mv[m + 1], a##S), mv[m + 1]);      \
    }                                                                        \
    read_ws[(blBase + (tt)) * Dd + d] = acc0 + acc1;                         \
    } while (0)

// ============ scan pass 1: per-chunk affine transfer (chunks 0..CCk-2) ============
// P/Q stored bf16 (compute fp32): halves scratch traffic.
__global__ void __launch_bounds__(128) kern_scan_pq(
        const int* __restrict__ skills,
        const int* __restrict__ responses,
        const float* __restrict__ wtab,
        const float* __restrict__ etab,
        const float* __restrict__ atab,
        bf16t* __restrict__ P_ws, bf16t* __restrict__ Q_ws) {
    int b = blockIdx.x / (CCk - 1), c = blockIdx.x % (CCk - 1);
    int d = threadIdx.x;
    int lane = d & 63;
    size_t blBase = (size_t)b * Ll + (size_t)c * TT;

    int skv = 0, xv = 0;
    if (lane < TT) {
        skv = skills[blBase + lane];
        int rr = responses[blBase + lane];
        xv = skv + NSs * ((rr > -1) ? rr : 0);
    }

    float P[Mm], Q[Mm];
#pragma unroll
    for (int m = 0; m < Mm; ++m) { P[m] = 1.f; Q[m] = 0.f; }

    float w0 = 0.f, e0 = 0.f, a0 = 0.f;
    float w1 = 0.f, e1 = 0.f, a1 = 0.f;
    float w2 = 0.f, e2 = 0.f, a2 = 0.f;
    TB_LOAD(0, 0);
    TB_LOAD(1, 1);
    for (int tt = 0; tt < TT; tt += 3) {
        TB_LOAD(2, tt + 2);  PQ_BODY(0);
        if (tt + 1 < TT) { TB_LOAD(0, tt + 3);  PQ_BODY(1); }
        if (tt + 2 < TT) { TB_LOAD(1, tt + 4);  PQ_BODY(2); }
    }
    size_t base = ((size_t)(b * (CCk - 1) + c)) * (Mm * Dd) + d;
#pragma unroll
    for (int m = 0; m < Mm; ++m) {
        P_ws[base + m * Dd] = __float2bfloat16(P[m]);
        Q_ws[base + m * Dd] = __float2bfloat16(Q[m]);
    }
}

// ============ scan pass 2: chunk-boundary combine (all loads hoisted, bf16 io) ============
__global__ void kern_scan_comb(
        const float* __restrict__ Mv0,
        const bf16t* __restrict__ P_ws, const bf16t* __restrict__ Q_ws,
        bf16t* __restrict__ S_ws) {
    int idx = blockIdx.x * 256 + threadIdx.x;     // 0 .. B*M*D-1
    int b   = idx / (Mm * Dd);
    int md  = idx % (Mm * Dd);
    float Pr[CCk - 1], Qr[CCk - 1];
#pragma unroll
    for (int c = 0; c < CCk - 1; ++c) {           // all loads issued together
        size_t pq = ((size_t)(b * (CCk - 1) + c)) * (Mm * Dd) + md;
        Pr[c] = __bfloat162float(P_ws[pq]);
        Qr[c] = __bfloat162float(Q_ws[pq]);
    }
    float s = Mv0[md];
#pragma unroll
    for (int c = 0; c < CCk - 1; ++c) {
        s = fmaf(Pr[c], s, Qr[c]);
        S_ws[((size_t)(b * (CCk - 1) + c)) * (Mm * Dd) + md] = __float2bfloat16(s);
    }
}

// ============ scan pass 3: rescan chunk from known start, emit read ============
__global__ void __launch_bounds__(128) kern_scan_rd(
        const int* __restrict__ skills,
        const int* __restrict__ responses,
        const float* __restrict__ Mv0,
        const float* __restrict__ wtab,
        const float* __restrict__ etab,
        const float* __restrict__ atab,
        const bf16t* __restrict__ S_ws,
        float* __restrict__ read_ws) {
    int b = blockIdx.x / CCk, c = blockIdx.x % CCk;
    int d = threadIdx.x;
    int lane = d & 63;
    size_t blBase = (size_t)b * Ll + (size_t)c * TT;

    int skv = 0, xv = 0;
    if (lane < TT) {
        skv = skills[blBase + lane];
        int rr = responses[blBase + lane];
        xv = skv + NSs * ((rr > -1) ? rr : 0);
    }

    float mv[Mm];
    if (c == 0) {
#pragma unroll
        for (int m = 0; m < Mm; ++m) mv[m] = Mv0[m * Dd + d];
    } else {
        size_t sb = ((size_t)(b * (CCk - 1) + (c - 1))) * (Mm * Dd) + d;
#pragma unroll
        for (int m = 0; m < Mm; ++m) mv[m] = __bfloat162float(S_ws[sb + m * Dd]);
    }

    float w0 = 0.f, e0 = 0.f, a0 = 0.f;
    float w1 = 0.f, e1 = 0.f, a1 = 0.f;
    float w2 = 0.f, e2 = 0.f, a2 = 0.f;
    TB_LOAD(0, 0);
    TB_LOAD(1, 1);
    for (int tt = 0; tt < TT; tt += 3) {
        TB_LOAD(2, tt + 2);  RD_BODY(0, tt);
        if (tt + 1 < TT) { TB_LOAD(0, tt + 3);  RD_BODY(1, tt + 1); }
        if (tt + 2 < TT) { TB_LOAD(1, tt + 4);  RD_BODY(2, tt + 2); }
    }
}

// ============ kernel 4: p = sigmoid(tanh(read·fW1 + fk[sk] + fb) @ pW^T + pb) ============
// 32 pos/block, 4 waves; K=128 (read half only). Lane tile 4 pos x 2 rows.
__global__ void __launch_bounds__(256) kern_out(
        const int* __restrict__ skills,
        const float* __restrict__ read_ws,
        const float* __restrict__ fktab,
        const float* __restrict__ f_W, const float* __restrict__ f_b,
        const float* __restrict__ p_W, const float* __restrict__ p_b,
        float* __restrict__ out) {
    __shared__ float ct[32][Dd + 4];           // read rows       (4224 f)
    __shared__ float fkt[32][Dd + 4];          // fk rows by sk   (4224 f)
    __shared__ float wt[4][16][Dd + 4];        // f_W read-half   (8448 f)
    __shared__ float pf[32][8];
    int tid = threadIdx.x;
    int blk = blockIdx.x;

#pragma unroll
    for (int i = 0; i < 4; ++i) {
        int lin = i * 256 + tid;
        int r = lin >> 5, c4 = lin & 31;
        int idx = blk * 32 + r;
        int b = idx / (Ll - 1);
        int l = idx % (Ll - 1) + 1;
        int bl = b * Ll + l;
        float4 f = ((const float4*)(read_ws + (size_t)bl * Dd))[c4];
        *(float4*)&ct[r][c4 * 4] = f;
        int sk = skills[bl];
        float4 g = ((const float4*)(fktab + (size_t)sk * Dd))[c4];
        *(float4*)&fkt[r][c4 * 4] = g;
    }
    ((float*)pf)[tid] = 0.f;
    __syncthreads();

    int wave = tid >> 6, lane = tid & 63;
    int pg = lane >> 3, og = lane & 7;

    float ppart[4] = {0.f, 0.f, 0.f, 0.f};
    for (int sub = 0; sub < 2; ++sub) {
        float acc[4][2] = {};
#pragma unroll
        for (int i = 0; i < 8; ++i) {
            int lin = i * 64 + lane;
            int r = lin >> 5, c4 = lin & 31;
            int row = wave * 32 + sub * 16 + r;
            float4 f = ((const float4*)(f_W + (size_t)row * (2 * Dd)))[c4];
            *(float4*)&wt[wave][r][c4 * 4] = f;
        }
        // wave-private tile: no barrier
#pragma unroll 2
        for (int q = 0; q < 32; ++q) {
            float4 av[4], bv[2];
#pragma unroll
            for (int i = 0; i < 4; ++i) av[i] = *(const float4*)&ct[pg + 8 * i][q * 4];
#pragma unroll
            for (int j = 0; j < 2; ++j) bv[j] = *(const float4*)&wt[wave][og + 8 * j][q * 4];
#pragma unroll
            for (int i = 0; i < 4; ++i)
#pragma unroll
                for (int j = 0; j < 2; ++j) {
                    acc[i][j] = fmaf(av[i].x, bv[j].x, acc[i][j]);
                    acc[i][j] = fmaf(av[i].y, bv[j].y, acc[i][j]);
                    acc[i][j] = fmaf(av[i].z, bv[j].z, acc[i][j]);
                    acc[i][j] = fmaf(av[i].w, bv[j].w, acc[i][j]);
                }
        }
#pragma unroll
        for (int j = 0; j < 2; ++j) {
            int row = wave * 32 + sub * 16 + og + 8 * j;
            float fb = f_b[row];
            float pw = p_W[row];
#pragma unroll
            for (int i = 0; i < 4; ++i) {
                float fkv = fkt[pg + 8 * i][row];
                ppart[i] = fmaf(tanhf(acc[i][j] + fkv + fb), pw, ppart[i]);
            }
        }
    }
#pragma unroll
    for (int i = 0; i < 4; ++i) {
        float v = ppart[i];
        for (int off = 4; off > 0; off >>= 1) v += __shfl_down(v, off, 8);
        if (og == 0) pf[pg + 8 * i][wave] = v;
    }
    __syncthreads();
    if (tid < 32) {
        float s = pf[tid][0] + pf[tid][1] + pf[tid][2] + pf[tid][3] + p_b[0];
        out[blk * 32 + tid] = 1.f / (1.f + expf(-s));
    }
}

extern "C" void kernel_launch(void* const* d_in, const int* in_sizes, int n_in,
                              void* d_out, int out_size, void* d_ws, size_t ws_size,
                              hipStream_t stream) {
    const int*   skills    = (const int*)  d_in[0];
    const int*   responses = (const int*)  d_in[1];
    const float* k_emb     = (const float*)d_in[2];
    const float* v_emb     = (const float*)d_in[3];
    const float* Mk        = (const float*)d_in[4];
    const float* Mv0       = (const float*)d_in[5];
    const float* e_W       = (const float*)d_in[6];
    const float* e_b       = (const float*)d_in[7];
    const float* a_W       = (const float*)d_in[8];
    const float* a_b       = (const float*)d_in[9];
    const float* f_W       = (const float*)d_in[10];
    const float* f_b       = (const float*)d_in[11];
    const float* p_W       = (const float*)d_in[12];
    const float* p_b       = (const float*)d_in[13];
    (void)in_sizes; (void)n_in; (void)out_size; (void)ws_size;

    float* out = (float*)d_out;

    const size_t BLD = (size_t)Bb * Ll * Dd;     // 1,638,400
    const size_t BMD = (size_t)Bb * Mm * Dd;     // 409,600

    float* ws      = (float*)d_ws;
    float* read_ws = ws;                                    // BLD floats
    bf16t* P_ws    = (bf16t*)(read_ws + BLD);               // (CCk-1)*BMD bf16
    bf16t* Q_ws    = P_ws + (size_t)(CCk - 1) * BMD;        // (CCk-1)*BMD bf16
    bf16t* S_ws    = Q_ws + (size_t)(CCk - 1) * BMD;        // (CCk-1)*BMD bf16
    float* wtab    = (float*)(S_ws + (size_t)(CCk - 1) * BMD);  // 1000*50
    float* etab    = wtab + (size_t)NSs * Mm;               // 2000*128
    float* atab    = etab + (size_t)2 * NSs * Dd;           // 2000*128
    float* fktab   = atab + (size_t)2 * NSs * Dd;           // 1000*128

    kern_tab<<<158, 256, 0, stream>>>(k_emb, v_emb, Mk, e_W, e_b, a_W, a_b, f_W,
                                      wtab, etab, atab, fktab);
    kern_scan_pq<<<Bb * (CCk - 1), 128, 0, stream>>>(skills, responses,
                                                     wtab, etab, atab, P_ws, Q_ws);
    kern_scan_comb<<<(int)(BMD / 256), 256, 0, stream>>>(Mv0, P_ws, Q_ws, S_ws);
    kern_scan_rd<<<Bb * CCk, 128, 0, stream>>>(skills, responses, Mv0,
                                               wtab, etab, atab, S_ws, read_ws);
    kern_out<<<Bb * (Ll - 1) / 32, 256, 0, stream>>>(skills, read_ws, fktab,
                                                     f_W, f_b, p_W, p_b, out);
}

// Round 16
// 155.497 us; speedup vs baseline: 1.2388x; 1.0202x over previous
//
#include <hip/hip_runtime.h>
#include <hip/hip_bf16.h>

#define Bb 64
#define Ll 200
#define NSs 1000
#define Dd 128
#define Mm 50
#define CCk 20           // scan chunks
#define TT 10            // steps per chunk

using bf16t = __hip_bfloat16;

__device__ __forceinline__ float bcast_lane(float v, int l) {
    return __int_as_float(__builtin_amdgcn_readlane(__float_as_int(v), l));
}
__device__ __forceinline__ unsigned int f2bfu(float f) {
    bf16t h = __float2bfloat16(f);
    return (unsigned int)*(unsigned short*)&h;
}
__device__ __forceinline__ float bfu2f(unsigned int u) {
    unsigned short s = (unsigned short)u;
    bf16t h = *(bf16t*)&s;
    return __bfloat162float(h);
}

// ============ kernel 1: precompute tables (dedupe by embedding index) ============
// blocks [0,63):   eatab rows x0=blk*32..   (2000 x-rows, interleaved {e,a})
// blocks [63,126): wtab rows sk0=(blk-63)*16.. (1000 sk-rows, softmax)
// blocks [126,158): fk rows sk0=(blk-126)*32.. (k-half of f GEMV, 1000 sk-rows)
__global__ void __launch_bounds__(256) kern_tab(
        const float* __restrict__ k_emb,
        const float* __restrict__ v_emb,
        const float* __restrict__ Mk,
        const float* __restrict__ e_W, const float* __restrict__ e_b,
        const float* __restrict__ a_W, const float* __restrict__ a_b,
        const float* __restrict__ f_W,
        float* __restrict__ wtab, float2* __restrict__ eatab,
        float* __restrict__ fktab) {
    __shared__ float smem[12672];                 // 50.7 KB union
    int tid = threadIdx.x;
    int wave = tid >> 6, lane = tid & 63;

    if (blockIdx.x >= 63 && blockIdx.x < 126) {
        int sk0 = (blockIdx.x - 63) * 16;
        float (*mk)[Dd + 4] = (float(*)[Dd + 4])smem;           // 6600 f
        float (*kr)[Dd + 4] = (float(*)[Dd + 4])(smem + 6600);  // 2112 f
        for (int lin = tid; lin < (Mm * Dd) / 4; lin += 256) {
            float4 f = ((const float4*)Mk)[lin];
            *(float4*)&mk[lin >> 5][(lin & 31) * 4] = f;
        }
        for (int lin = tid; lin < 16 * 32; lin += 256) {
            int r = lin >> 5, c4 = lin & 31;
            int sk = min(sk0 + r, NSs - 1);
            float4 f = ((const float4*)(k_emb + (size_t)sk * Dd))[c4];
            *(float4*)&kr[r][c4 * 4] = f;
        }
        __syncthreads();
        int mmr = (lane < Mm) ? lane : 0;
        float acc[4] = {0.f, 0.f, 0.f, 0.f};
#pragma unroll 2
        for (int q = 0; q < 32; ++q) {
            float4 mkv = *(const float4*)&mk[mmr][q * 4];
#pragma unroll
            for (int i = 0; i < 4; ++i) {
                float4 kv = *(const float4*)&kr[wave * 4 + i][q * 4];
                acc[i] = fmaf(mkv.x, kv.x, acc[i]);
                acc[i] = fmaf(mkv.y, kv.y, acc[i]);
                acc[i] = fmaf(mkv.z, kv.z, acc[i]);
                acc[i] = fmaf(mkv.w, kv.w, acc[i]);
            }
        }
#pragma unroll
        for (int i = 0; i < 4; ++i) {
            float logit = (lane < Mm) ? acc[i] : -1e30f;
            float mx = logit;
            for (int off = 32; off > 0; off >>= 1) mx = fmaxf(mx, __shfl_down(mx, off));
            mx = __shfl(mx, 0);
            float ex = (lane < Mm) ? expf(logit - mx) : 0.f;
            float sm = ex;
            for (int off = 32; off > 0; off >>= 1) sm += __shfl_down(sm, off);
            sm = __shfl(sm, 0);
            int sk = sk0 + wave * 4 + i;
            if (sk < NSs && lane < Mm) wtab[(size_t)sk * Mm + lane] = ex / sm;
        }
        return;
    }

    bool is_fk = (blockIdx.x >= 126);
    int r0 = is_fk ? (blockIdx.x - 126) * 32 : blockIdx.x * 32;
    int rmax = is_fk ? NSs : 2 * NSs;
    const float* src = is_fk ? k_emb : v_emb;

    float (*vt)[Dd + 4] = (float(*)[Dd + 4])smem;           // 4224 f
    float (*wt)[Dd + 4] = (float(*)[Dd + 4])(smem + 4224);  // 8448 f
#pragma unroll
    for (int i = 0; i < 4; ++i) {
        int lin = i * 256 + tid;
        int r = lin >> 5, c4 = lin & 31;
        int x = min(r0 + r, rmax - 1);
        float4 f = ((const float4*)(src + (size_t)x * Dd))[c4];
        *(float4*)&vt[r][c4 * 4] = f;
    }
    __syncthreads();
    int pg = lane >> 3, og = lane & 7;

    if (is_fk) {
        for (int sub = 0; sub < 2; ++sub) {
#pragma unroll
            for (int i = 0; i < 8; ++i) {
                int lin = i * 64 + lane;
                int r = lin >> 5, c4 = lin & 31;
                int row = wave * 32 + sub * 16 + r;
                float4 f = ((const float4*)(f_W + (size_t)row * (2 * Dd)))[32 + c4];
                *(float4*)&wt[wave * 16 + r][c4 * 4] = f;
            }
            float acc[4][2] = {};
#pragma unroll 2
            for (int q = 0; q < 32; ++q) {
                float4 av[4], bv[2];
#pragma unroll
                for (int i = 0; i < 4; ++i) av[i] = *(const float4*)&vt[pg + 8 * i][q * 4];
#pragma unroll
                for (int j = 0; j < 2; ++j) bv[j] = *(const float4*)&wt[wave * 16 + og + 8 * j][q * 4];
#pragma unroll
                for (int i = 0; i < 4; ++i)
#pragma unroll
                    for (int j = 0; j < 2; ++j) {
                        acc[i][j] = fmaf(av[i].x, bv[j].x, acc[i][j]);
                        acc[i][j] = fmaf(av[i].y, bv[j].y, acc[i][j]);
                        acc[i][j] = fmaf(av[i].z, bv[j].z, acc[i][j]);
                        acc[i][j] = fmaf(av[i].w, bv[j].w, acc[i][j]);
                    }
            }
#pragma unroll
            for (int j = 0; j < 2; ++j) {
                int row = wave * 32 + sub * 16 + og + 8 * j;
#pragma unroll
                for (int i = 0; i < 4; ++i) {
                    int sk = r0 + pg + 8 * i;
                    if (sk < NSs) fktab[(size_t)sk * Dd + row] = acc[i][j];
                }
            }
        }
    } else {
        float* dstf = (float*)eatab;              // interleaved {e, a}
        for (int s = 0; s < 4; ++s) {
            int base_row = wave * 64 + s * 16;
            bool is_e = base_row < 128;
            const float* W = is_e ? e_W : a_W;
            int wrow0 = is_e ? base_row : base_row - 128;
#pragma unroll
            for (int i = 0; i < 8; ++i) {
                int lin = i * 64 + lane;
                int r = lin >> 5, c4 = lin & 31;
                float4 f = ((const float4*)(W + (size_t)(wrow0 + r) * Dd))[c4];
                *(float4*)&wt[wave * 16 + r][c4 * 4] = f;
            }
            float acc[4][2] = {};
#pragma unroll 2
            for (int q = 0; q < 32; ++q) {
                float4 av[4], bv[2];
#pragma unroll
                for (int i = 0; i < 4; ++i) av[i] = *(const float4*)&vt[pg + 8 * i][q * 4];
#pragma unroll
                for (int j = 0; j < 2; ++j) bv[j] = *(const float4*)&wt[wave * 16 + og + 8 * j][q * 4];
#pragma unroll
                for (int i = 0; i < 4; ++i)
#pragma unroll
                    for (int j = 0; j < 2; ++j) {
                        acc[i][j] = fmaf(av[i].x, bv[j].x, acc[i][j]);
                        acc[i][j] = fmaf(av[i].y, bv[j].y, acc[i][j]);
                        acc[i][j] = fmaf(av[i].z, bv[j].z, acc[i][j]);
                        acc[i][j] = fmaf(av[i].w, bv[j].w, acc[i][j]);
                    }
            }
#pragma unroll
            for (int j = 0; j < 2; ++j) {
                int row = wrow0 + og + 8 * j;
                float bias = (is_e ? e_b : a_b)[row];
#pragma unroll
                for (int i = 0; i < 4; ++i) {
                    int x = r0 + pg + 8 * i;
                    if (x < 2 * NSs) {
                        float v = acc[i][j] + bias;
                        float r = is_e ? (1.f / (1.f + expf(-v))) : tanhf(v);
                        dstf[((size_t)x * Dd + row) * 2 + (is_e ? 0 : 1)] = r;
                    }
                }
            }
        }
    }
}

#define TB_LOAD(S, tt) do { int _t = (tt);                                   \
    if (_t < TT) {                                                           \
        int _sk = __shfl(skv, _t);                                           \
        int _x  = __shfl(xv, _t);                                            \
        w##S = (lane < Mm) ? wtab[(size_t)_sk * Mm + lane] : 0.f;            \
        float2 _ea = eatab[(size_t)_x * Dd + d];                             \
        e##S = _ea.x;  a##S = _ea.y; } } while (0)

#define PQ_BODY(S) do {                                                      \
    _Pragma("unroll")                                                        \
    for (int m = 0; m < Mm; ++m) {                                           \
        float wm = bcast_lane(w##S, m);                                      \
        float A  = fmaf(-wm, e##S, 1.f);                                     \
        Q[m] = fmaf(A, Q[m], wm * a##S);                                     \
        P[m] *= A; } } while (0)

#define RD_BODY(S, tt) do {                                                  \
    float acc0 = 0.f, acc1 = 0.f;                                            \
    _Pragma("unroll")                                                        \
    for (int m = 0; m < Mm; m += 2) {                                        \
        float wm0 = bcast_lane(w##S, m);                                     \
        float wm1 = bcast_lane(w##S, m + 1);                                 \
        acc0 = fmaf(wm0, mv[m], acc0);                                       \
        mv[m] = fmaf(wm0, fmaf(-e##S, mv[m], a##S), mv[m]);                  \
        acc1 = fmaf(wm1, mv[m + 1], acc1);                                   \
        mv[m + 1] = fmaf(wm1, fmaf(-e##S, mv[m + 1], a##S), mv[m + 1]);      \
    }                                                                        \
    read_ws[(blBase + (tt)) * Dd + d] = acc0 + acc1;                         \
    } while (0)

// ============ scan pass 1: per-chunk affine transfer (chunks 0..CCk-2) ============
// P,Q packed bf16x2 into one uint (compute fp32): half the scratch memory ops.
__global__ void __launch_bounds__(128) kern_scan_pq(
        const int* __restrict__ skills,
        const int* __restrict__ responses,
        const float* __restrict__ wtab,
        const float2* __restrict__ eatab,
        unsigned int* __restrict__ PQ_ws) {
    int b = blockIdx.x / (CCk - 1), c = blockIdx.x % (CCk - 1);
    int d = threadIdx.x;
    int lane = d & 63;
    size_t blBase = (size_t)b * Ll + (size_t)c * TT;

    int skv = 0, xv = 0;
    if (lane < TT) {
        skv = skills[blBase + lane];
        int rr = responses[blBase + lane];
        xv = skv + NSs * ((rr > -1) ? rr : 0);
    }

    float P[Mm], Q[Mm];
#pragma unroll
    for (int m = 0; m < Mm; ++m) { P[m] = 1.f; Q[m] = 0.f; }

    float w0 = 0.f, e0 = 0.f, a0 = 0.f;
    float w1 = 0.f, e1 = 0.f, a1 = 0.f;
    float w2 = 0.f, e2 = 0.f, a2 = 0.f;
    TB_LOAD(0, 0);
    TB_LOAD(1, 1);
    for (int tt = 0; tt < TT; tt += 3) {
        TB_LOAD(2, tt + 2);  PQ_BODY(0);
        if (tt + 1 < TT) { TB_LOAD(0, tt + 3);  PQ_BODY(1); }
        if (tt + 2 < TT) { TB_LOAD(1, tt + 4);  PQ_BODY(2); }
    }
    size_t base = ((size_t)(b * (CCk - 1) + c)) * (Mm * Dd) + d;
#pragma unroll
    for (int m = 0; m < Mm; ++m)
        PQ_ws[base + m * Dd] = f2bfu(P[m]) | (f2bfu(Q[m]) << 16);
}

// ============ scan pass 2: chunk-boundary combine (hoisted packed loads) ============
__global__ void kern_scan_comb(
        const float* __restrict__ Mv0,
        const unsigned int* __restrict__ PQ_ws,
        bf16t* __restrict__ S_ws) {
    int idx = blockIdx.x * 256 + threadIdx.x;     // 0 .. B*M*D-1
    int b   = idx / (Mm * Dd);
    int md  = idx % (Mm * Dd);
    unsigned int PQr[CCk - 1];
#pragma unroll
    for (int c = 0; c < CCk - 1; ++c) {           // all loads issued together
        size_t pq = ((size_t)(b * (CCk - 1) + c)) * (Mm * Dd) + md;
        PQr[c] = PQ_ws[pq];
    }
    float s = Mv0[md];
#pragma unroll
    for (int c = 0; c < CCk - 1; ++c) {
        s = fmaf(bfu2f(PQr[c] & 0xffffu), s, bfu2f(PQr[c] >> 16));
        S_ws[((size_t)(b * (CCk - 1) + c)) * (Mm * Dd) + md] = __float2bfloat16(s);
    }
}

// ============ scan pass 3: rescan chunk from known start, emit read ============
__global__ void __launch_bounds__(128) kern_scan_rd(
        const int* __restrict__ skills,
        const int* __restrict__ responses,
        const float* __restrict__ Mv0,
        const float* __restrict__ wtab,
        const float2* __restrict__ eatab,
        const bf16t* __restrict__ S_ws,
        float* __restrict__ read_ws) {
    int b = blockIdx.x / CCk, c = blockIdx.x % CCk;
    int d = threadIdx.x;
    int lane = d & 63;
    size_t blBase = (size_t)b * Ll + (size_t)c * TT;

    int skv = 0, xv = 0;
    if (lane < TT) {
        skv = skills[blBase + lane];
        int rr = responses[blBase + lane];
        xv = skv + NSs * ((rr > -1) ? rr : 0);
    }

    float mv[Mm];
    if (c == 0) {
#pragma unroll
        for (int m = 0; m < Mm; ++m) mv[m] = Mv0[m * Dd + d];
    } else {
        size_t sb = ((size_t)(b * (CCk - 1) + (c - 1))) * (Mm * Dd) + d;
#pragma unroll
        for (int m = 0; m < Mm; ++m) mv[m] = __bfloat162float(S_ws[sb + m * Dd]);
    }

    float w0 = 0.f, e0 = 0.f, a0 = 0.f;
    float w1 = 0.f, e1 = 0.f, a1 = 0.f;
    float w2 = 0.f, e2 = 0.f, a2 = 0.f;
    TB_LOAD(0, 0);
    TB_LOAD(1, 1);
    for (int tt = 0; tt < TT; tt += 3) {
        TB_LOAD(2, tt + 2);  RD_BODY(0, tt);
        if (tt + 1 < TT) { TB_LOAD(0, tt + 3);  RD_BODY(1, tt + 1); }
        if (tt + 2 < TT) { TB_LOAD(1, tt + 4);  RD_BODY(2, tt + 2); }
    }
}

// ============ kernel 4: p = sigmoid(tanh(read·fW1 + fk[sk] + fb) @ pW^T + pb) ============
// 32 pos/block, 4 waves; K=128 (read half only). Lane tile 4 pos x 2 rows.
__global__ void __launch_bounds__(256) kern_out(
        const int* __restrict__ skills,
        const float* __restrict__ read_ws,
        const float* __restrict__ fktab,
        const float* __restrict__ f_W, const float* __restrict__ f_b,
        const float* __restrict__ p_W, const float* __restrict__ p_b,
        float* __restrict__ out) {
    __shared__ float ct[32][Dd + 4];           // read rows       (4224 f)
    __shared__ float fkt[32][Dd + 4];          // fk rows by sk   (4224 f)
    __shared__ float wt[4][16][Dd + 4];        // f_W read-half   (8448 f)
    __shared__ float pf[32][8];
    int tid = threadIdx.x;
    int blk = blockIdx.x;

#pragma unroll
    for (int i = 0; i < 4; ++i) {
        int lin = i * 256 + tid;
        int r = lin >> 5, c4 = lin & 31;
        int idx = blk * 32 + r;
        int b = idx / (Ll - 1);
        int l = idx % (Ll - 1) + 1;
        int bl = b * Ll + l;
        float4 f = ((const float4*)(read_ws + (size_t)bl * Dd))[c4];
        *(float4*)&ct[r][c4 * 4] = f;
        int sk = skills[bl];
        float4 g = ((const float4*)(fktab + (size_t)sk * Dd))[c4];
        *(float4*)&fkt[r][c4 * 4] = g;
    }
    ((float*)pf)[tid] = 0.f;
    __syncthreads();

    int wave = tid >> 6, lane = tid & 63;
    int pg = lane >> 3, og = lane & 7;

    float ppart[4] = {0.f, 0.f, 0.f, 0.f};
    for (int sub = 0; sub < 2; ++sub) {
        float acc[4][2] = {};
#pragma unroll
        for (int i = 0; i < 8; ++i) {
            int lin = i * 64 + lane;
            int r = lin >> 5, c4 = lin & 31;
            int row = wave * 32 + sub * 16 + r;
            float4 f = ((const float4*)(f_W + (size_t)row * (2 * Dd)))[c4];
            *(float4*)&wt[wave][r][c4 * 4] = f;
        }
        // wave-private tile: no barrier
#pragma unroll 2
        for (int q = 0; q < 32; ++q) {
            float4 av[4], bv[2];
#pragma unroll
            for (int i = 0; i < 4; ++i) av[i] = *(const float4*)&ct[pg + 8 * i][q * 4];
#pragma unroll
            for (int j = 0; j < 2; ++j) bv[j] = *(const float4*)&wt[wave][og + 8 * j][q * 4];
#pragma unroll
            for (int i = 0; i < 4; ++i)
#pragma unroll
                for (int j = 0; j < 2; ++j) {
                    acc[i][j] = fmaf(av[i].x, bv[j].x, acc[i][j]);
                    acc[i][j] = fmaf(av[i].y, bv[j].y, acc[i][j]);
                    acc[i][j] = fmaf(av[i].z, bv[j].z, acc[i][j]);
                    acc[i][j] = fmaf(av[i].w, bv[j].w, acc[i][j]);
                }
        }
#pragma unroll
        for (int j = 0; j < 2; ++j) {
            int row = wave * 32 + sub * 16 + og + 8 * j;
            float fb = f_b[row];
            float pw = p_W[row];
#pragma unroll
            for (int i = 0; i < 4; ++i) {
                float fkv = fkt[pg + 8 * i][row];
                ppart[i] = fmaf(tanhf(acc[i][j] + fkv + fb), pw, ppart[i]);
            }
        }
    }
#pragma unroll
    for (int i = 0; i < 4; ++i) {
        float v = ppart[i];
        for (int off = 4; off > 0; off >>= 1) v += __shfl_down(v, off, 8);
        if (og == 0) pf[pg + 8 * i][wave] = v;
    }
    __syncthreads();
    if (tid < 32) {
        float s = pf[tid][0] + pf[tid][1] + pf[tid][2] + pf[tid][3] + p_b[0];
        out[blk * 32 + tid] = 1.f / (1.f + expf(-s));
    }
}

extern "C" void kernel_launch(void* const* d_in, const int* in_sizes, int n_in,
                              void* d_out, int out_size, void* d_ws, size_t ws_size,
                              hipStream_t stream) {
    const int*   skills    = (const int*)  d_in[0];
    const int*   responses = (const int*)  d_in[1];
    const float* k_emb     = (const float*)d_in[2];
    const float* v_emb     = (const float*)d_in[3];
    const float* Mk        = (const float*)d_in[4];
    const float* Mv0       = (const float*)d_in[5];
    const float* e_W       = (const float*)d_in[6];
    const float* e_b       = (const float*)d_in[7];
    const float* a_W       = (const float*)d_in[8];
    const float* a_b       = (const float*)d_in[9];
    const float* f_W       = (const float*)d_in[10];
    const float* f_b       = (const float*)d_in[11];
    const float* p_W       = (const float*)d_in[12];
    const float* p_b       = (const float*)d_in[13];
    (void)in_sizes; (void)n_in; (void)out_size; (void)ws_size;

    float* out = (float*)d_out;

    const size_t BLD = (size_t)Bb * Ll * Dd;     // 1,638,400
    const size_t BMD = (size_t)Bb * Mm * Dd;     // 409,600

    float*        ws      = (float*)d_ws;
    float*        read_ws = ws;                                       // BLD floats
    unsigned int* PQ_ws   = (unsigned int*)(read_ws + BLD);           // (CCk-1)*BMD uint
    bf16t*        S_ws    = (bf16t*)(PQ_ws + (size_t)(CCk - 1) * BMD);// (CCk-1)*BMD bf16
    float*        wtab    = (float*)(S_ws + (size_t)(CCk - 1) * BMD); // 1000*50
    float2*       eatab   = (float2*)(wtab + (size_t)NSs * Mm);       // 2000*128 float2
    float*        fktab   = (float*)(eatab + (size_t)2 * NSs * Dd);   // 1000*128

    kern_tab<<<158, 256, 0, stream>>>(k_emb, v_emb, Mk, e_W, e_b, a_W, a_b, f_W,
                                      wtab, eatab, fktab);
    kern_scan_pq<<<Bb * (CCk - 1), 128, 0, stream>>>(skills, responses,
                                                     wtab, eatab, PQ_ws);
    kern_scan_comb<<<(int)(BMD / 256), 256, 0, stream>>>(Mv0, PQ_ws, S_ws);
    kern_scan_rd<<<Bb * CCk, 128, 0, stream>>>(skills, responses, Mv0,
                                               wtab, eatab, S_ws, read_ws);
    kern_out<<<Bb * (Ll - 1) / 32, 256, 0, stream>>>(skills, read_ws, fktab,
                                                     f_W, f_b, p_W, p_b, out);
}